// Round 1
// baseline (333.007 us; speedup 1.0000x reference)
//
#include <hip/hip_runtime.h>

typedef unsigned short u16;
typedef __attribute__((ext_vector_type(4))) float f4;
typedef __attribute__((ext_vector_type(8))) short bf8;
typedef __attribute__((ext_vector_type(4))) unsigned short u16x4;

#define B_ 8
#define C_ 512
#define T_ 2048
#define S_ 2048
#define SCALE_W 0.70710678118654752440f

__device__ __forceinline__ u16 f2bf(float f) {
  unsigned u = __builtin_bit_cast(unsigned, f);
  unsigned r = 0x7FFFu + ((u >> 16) & 1u);
  return (u16)((u + r) >> 16);
}
__device__ __forceinline__ float bf2f(u16 h) {
  unsigned u = ((unsigned)h) << 16;
  return __builtin_bit_cast(float, u);
}

__device__ __forceinline__ void gload16(const u16* g, u16* l) {
  __builtin_amdgcn_global_load_lds((__attribute__((address_space(1))) const void*)g,
                                   (__attribute__((address_space(3))) void*)l, 16, 0, 0);
}

// ---------- prep: transpose [B,C,X] -> [B,X,C], split to bf16 hi/lo (MODE 0) or f32 copy (MODE 1)
template<int MODE>
__global__ __launch_bounds__(256) void transpose_kernel(
    const float* __restrict__ in, u16* __restrict__ oh, u16* __restrict__ ol,
    float* __restrict__ of, int X)
{
  __shared__ float t[32][33];
  const int tx = threadIdx.x, ty = threadIdx.y;
  const long cbase = (long)blockIdx.z * C_ + blockIdx.y * 32;
  const long xbase = (long)blockIdx.x * 32;
  const float* ip = in + cbase * X + xbase;
#pragma unroll
  for (int i = 0; i < 4; ++i)
    t[ty + i * 8][tx] = ip[(long)(ty + i * 8) * X + tx];
  __syncthreads();
  const long obase = ((long)blockIdx.z * X + xbase) * C_ + blockIdx.y * 32;
#pragma unroll
  for (int i = 0; i < 4; ++i) {
    float v = t[tx][ty + i * 8];
    long idx = obase + (long)(ty + i * 8) * C_ + tx;
    if (MODE == 0) {
      u16 h = f2bf(v);
      oh[idx] = h;
      ol[idx] = f2bf(v - bf2f(h));
    } else {
      of[idx] = v;
    }
  }
}

// ---------- prep: elementwise split f32 -> bf16 hi (and optional lo), no transpose
__global__ __launch_bounds__(256) void split_kernel(
    const float* __restrict__ in, u16* __restrict__ oh, u16* __restrict__ ol, long n4)
{
  long i = (long)blockIdx.x * 256 + threadIdx.x;
  const long stride = (long)gridDim.x * 256;
  for (; i < n4; i += stride) {
    f4 v = ((const f4*)in)[i];
    u16x4 hv, lv;
#pragma unroll
    for (int j = 0; j < 4; ++j) {
      u16 h = f2bf(v[j]);
      hv[j] = h;
      lv[j] = f2bf(v[j] - bf2f(h));
    }
    ((u16x4*)oh)[i] = hv;
    if (ol) ((u16x4*)ol)[i] = lv;
  }
}

// ---------- GEMM: out[M][N] = A[M][K] * B[N][K]^T  (both operands K-contiguous rows)
// NPASS=3: hi/lo split 3-pass accumulate (near-f32). NPASS=1: plain bf16.
// EPI=1: target epilogue (+baseT +bias, *SCALE, split-store hi/lo). EPI=0: f32 store.
// BF32=1: B operand is f32 in global, converted to bf16 during reg-staging.
template<int NPASS, int EPI, int BF32>
__global__ __launch_bounds__(256, 2) void gemm_kernel(
    const u16* __restrict__ Ah, const u16* __restrict__ Al,
    const u16* __restrict__ Bh, const u16* __restrict__ Bl,
    const float* __restrict__ Bf,
    int M, int N, int K,
    long sA, long sB, long sO,
    const float* __restrict__ baseT, const float* __restrict__ bias,
    u16* __restrict__ outH, u16* __restrict__ outL,
    float* __restrict__ outF)
{
  constexpr int BM = 128, BN = 128, BK = 32;
  constexpr int TILE = BM * BK;
  __shared__ u16 lA[(NPASS == 3 ? 2 : 1) * TILE];
  __shared__ u16 lB[(NPASS == 3 ? 2 : 1) * TILE];
  u16* lAh = lA; u16* lAl = (NPASS == 3) ? (lA + TILE) : lA;
  u16* lBh = lB; u16* lBl = (NPASS == 3) ? (lB + TILE) : lB;

  const int tid = threadIdx.x;
  const int wid = tid >> 6;
  const int lane = tid & 63;
  const int wr = wid >> 1, wc = wid & 1;
  const int bz = blockIdx.z;
  const int m0 = blockIdx.y * BM;
  const int n0 = blockIdx.x * BN;

  const u16* gAh = Ah + (long)bz * sA + (long)m0 * K;
  const u16* gAl = (NPASS == 3) ? (Al + (long)bz * sA + (long)m0 * K) : nullptr;
  const u16* gBh = (!BF32) ? (Bh + (long)bz * sB + (long)n0 * K) : nullptr;
  const u16* gBl = (NPASS == 3) ? (Bl + (long)bz * sB + (long)n0 * K) : nullptr;
  const float* gBf = BF32 ? (Bf + (long)bz * sB + (long)n0 * K) : nullptr;

  const int srow = tid >> 2;         // staging row 0..63 (per 64-row half)
  const int skoff = (tid & 3) * 8;   // staging k-offset (elements)
  const int ldsOff = wid * 512;      // wave-uniform LDS dest (u16 units)

  f4 acc[4][4] = {};

  for (int k0 = 0; k0 < K; k0 += BK) {
    __syncthreads();
#pragma unroll
    for (int c = 0; c < 2; ++c) {
      const long go = (long)(c * 64 + srow) * K + k0 + skoff;
      const int lo = c * 2048 + ldsOff;
      gload16(gAh + go, lAh + lo);
      if (NPASS == 3) gload16(gAl + go, lAl + lo);
      if (!BF32) {
        gload16(gBh + go, lBh + lo);
        if (NPASS == 3) gload16(gBl + go, lBl + lo);
      }
    }
    if (BF32) {
      const int n = tid >> 1;
      const int kh = (tid & 1) * 16;
      const float* src = gBf + (long)n * K + k0 + kh;
      f4 f0 = *(const f4*)(src);
      f4 f1 = *(const f4*)(src + 4);
      f4 f2 = *(const f4*)(src + 8);
      f4 f3 = *(const f4*)(src + 12);
      bf8 p0, p1;
#pragma unroll
      for (int j = 0; j < 4; ++j) {
        p0[j]     = (short)f2bf(f0[j]);
        p0[4 + j] = (short)f2bf(f1[j]);
        p1[j]     = (short)f2bf(f2[j]);
        p1[4 + j] = (short)f2bf(f3[j]);
      }
      *(bf8*)&lBh[n * BK + kh] = p0;
      *(bf8*)&lBh[n * BK + kh + 8] = p1;
    }
    asm volatile("s_waitcnt vmcnt(0)" ::: "memory");
    __syncthreads();

    bf8 a_h[4], b_h[4], a_l[4], b_l[4];
    const int fr = lane & 15;
    const int fk = (lane >> 4) * 8;
#pragma unroll
    for (int i = 0; i < 4; ++i) {
      a_h[i] = *(const bf8*)&lAh[(wr * 64 + i * 16 + fr) * BK + fk];
      b_h[i] = *(const bf8*)&lBh[(wc * 64 + i * 16 + fr) * BK + fk];
      if (NPASS == 3) {
        a_l[i] = *(const bf8*)&lAl[(wr * 64 + i * 16 + fr) * BK + fk];
        b_l[i] = *(const bf8*)&lBl[(wc * 64 + i * 16 + fr) * BK + fk];
      }
    }
#pragma unroll
    for (int mi = 0; mi < 4; ++mi)
#pragma unroll
      for (int ni = 0; ni < 4; ++ni) {
        acc[mi][ni] = __builtin_amdgcn_mfma_f32_16x16x32_bf16(a_h[mi], b_h[ni], acc[mi][ni], 0, 0, 0);
        if (NPASS == 3) {
          acc[mi][ni] = __builtin_amdgcn_mfma_f32_16x16x32_bf16(a_h[mi], b_l[ni], acc[mi][ni], 0, 0, 0);
          acc[mi][ni] = __builtin_amdgcn_mfma_f32_16x16x32_bf16(a_l[mi], b_h[ni], acc[mi][ni], 0, 0, 0);
        }
      }
  }

  const int fr = lane & 15;
  const int r4 = (lane >> 4) * 4;
#pragma unroll
  for (int mi = 0; mi < 4; ++mi) {
#pragma unroll
    for (int ni = 0; ni < 4; ++ni) {
      const int gn = n0 + wc * 64 + ni * 16 + fr;
#pragma unroll
      for (int r = 0; r < 4; ++r) {
        const long gm = m0 + wr * 64 + mi * 16 + r4 + r;
        const long idx = (long)bz * sO + gm * (long)N + gn;
        const float v = acc[mi][ni][r];
        if (EPI == 1) {
          float val = (v + baseT[idx] + bias[gn]) * SCALE_W;
          u16 h = f2bf(val);
          outH[idx] = h;
          outL[idx] = f2bf(val - bf2f(h));
        } else {
          outF[idx] = v;
        }
      }
    }
  }
}

// ---------- softmax over last dim (rows of 2048 f32), in place
__global__ __launch_bounds__(256) void softmax_kernel(float* __restrict__ a) {
  const int tid = threadIdx.x;
  float* p = a + (long)blockIdx.x * 2048;
  f4 v0 = ((const f4*)p)[tid];
  f4 v1 = ((const f4*)p)[tid + 256];
  float m = fmaxf(fmaxf(fmaxf(v0[0], v0[1]), fmaxf(v0[2], v0[3])),
                  fmaxf(fmaxf(v1[0], v1[1]), fmaxf(v1[2], v1[3])));
#pragma unroll
  for (int o = 32; o >= 1; o >>= 1) m = fmaxf(m, __shfl_xor(m, o));
  __shared__ float redm[4], reds[4];
  if ((tid & 63) == 0) redm[tid >> 6] = m;
  __syncthreads();
  m = fmaxf(fmaxf(redm[0], redm[1]), fmaxf(redm[2], redm[3]));
  float s = 0.f;
#pragma unroll
  for (int j = 0; j < 4; ++j) { v0[j] = __expf(v0[j] - m); s += v0[j]; }
#pragma unroll
  for (int j = 0; j < 4; ++j) { v1[j] = __expf(v1[j] - m); s += v1[j]; }
#pragma unroll
  for (int o = 32; o >= 1; o >>= 1) s += __shfl_xor(s, o);
  if ((tid & 63) == 0) reds[tid >> 6] = s;
  __syncthreads();
  const float inv = 1.0f / (reds[0] + reds[1] + reds[2] + reds[3]);
  v0 *= inv; v1 *= inv;
  ((f4*)p)[tid] = v0;
  ((f4*)p)[tid + 256] = v1;
}

extern "C" void kernel_launch(void* const* d_in, const int* in_sizes, int n_in,
                              void* d_out, int out_size, void* d_ws, size_t ws_size,
                              hipStream_t stream) {
  const float* base  = (const float*)d_in[0];
  const float* x     = (const float*)d_in[1];
  const float* enc_t = (const float*)d_in[2];
  const float* enc_c = (const float*)d_in[3];
  const float* W     = (const float*)d_in[4];
  const float* bias  = (const float*)d_in[5];

  float* ctx  = (float*)d_out;                       // [B,C,T]
  float* attn = ctx + (long)B_ * C_ * T_;            // [B,T,S]

  const long NBTC = (long)B_ * T_ * C_;              // 8388608
  u16* x_hi  = (u16*)d_ws;
  u16* x_lo  = x_hi + NBTC;
  u16* et_hi = x_lo + NBTC;
  u16* et_lo = et_hi + NBTC;
  u16* ec_hi = et_lo + NBTC;
  float* baseT = (float*)(ec_hi + NBTC);
  u16* w_hi  = (u16*)(baseT + NBTC);
  u16* w_lo  = w_hi + (long)C_ * C_;

  // target hi/lo splits live in the d_out ctx region (dead until final GEMM)
  u16* t_hi = (u16*)d_out;
  u16* t_lo = t_hi + NBTC;

  dim3 tb(32, 8);
  // x [B,C,T] -> x_hi/x_lo [B,T,C]
  transpose_kernel<0><<<dim3(T_ / 32, C_ / 32, B_), tb, 0, stream>>>(x, x_hi, x_lo, nullptr, T_);
  // base [B,C,T] -> baseT [B,T,C] f32
  transpose_kernel<1><<<dim3(T_ / 32, C_ / 32, B_), tb, 0, stream>>>(base, nullptr, nullptr, baseT, T_);
  // enc_t [B,C,S] -> et_hi/et_lo [B,S,C]
  transpose_kernel<0><<<dim3(S_ / 32, C_ / 32, B_), tb, 0, stream>>>(enc_t, et_hi, et_lo, nullptr, S_);
  // enc_c [B,C,S] -> ec_hi bf16 (no transpose, hi only)
  split_kernel<<<2048, 256, 0, stream>>>(enc_c, ec_hi, nullptr, (long)B_ * C_ * S_ / 4);
  // W -> w_hi/w_lo
  split_kernel<<<256, 256, 0, stream>>>(W, w_hi, w_lo, (long)C_ * C_ / 4);

  // GEMM1: target^T[t][o] = sum_c x^T[t][c] * W[o][c]; epilogue +baseT +bias, *scale, split
  gemm_kernel<3, 1, 0><<<dim3(C_ / 128, T_ / 128, B_), 256, 0, stream>>>(
      x_hi, x_lo, w_hi, w_lo, nullptr,
      T_, C_, C_, (long)T_ * C_, 0L, (long)T_ * C_,
      baseT, bias, t_hi, t_lo, nullptr);

  // GEMM2: pre_a[t][s] = sum_c target^T[t][c] * et[s][c]  -> attn region (f32)
  gemm_kernel<3, 0, 0><<<dim3(S_ / 128, T_ / 128, B_), 256, 0, stream>>>(
      t_hi, t_lo, et_hi, et_lo, nullptr,
      T_, S_, C_, (long)T_ * C_, (long)S_ * C_, (long)T_ * S_,
      nullptr, nullptr, nullptr, nullptr, attn);

  // softmax rows in place
  softmax_kernel<<<B_ * T_, 256, 0, stream>>>(attn);

  // GEMM3: ctx[c][t] = sum_s ec[c][s] * attn[t][s]  (B operand f32 -> bf16 reg-staged)
  gemm_kernel<1, 0, 1><<<dim3(T_ / 128, C_ / 128, B_), 256, 0, stream>>>(
      ec_hi, nullptr, nullptr, nullptr, attn,
      C_, T_, S_, (long)C_ * S_, (long)T_ * S_, (long)C_ * T_,
      nullptr, nullptr, nullptr, nullptr, ctx);

  (void)in_sizes; (void)n_in; (void)out_size; (void)ws_size;
}

// Round 2
// 326.255 us; speedup vs baseline: 1.0207x; 1.0207x over previous
//
#include <hip/hip_runtime.h>

typedef unsigned short u16;
typedef __attribute__((ext_vector_type(4))) float f4;
typedef __attribute__((ext_vector_type(8))) short bf8;
typedef __attribute__((ext_vector_type(4))) unsigned short u16x4;

#define B_ 8
#define C_ 512
#define T_ 2048
#define S_ 2048
#define SCALE_W 0.70710678118654752440f

__device__ __forceinline__ u16 f2bf(float f) {
  unsigned u = __builtin_bit_cast(unsigned, f);
  unsigned r = 0x7FFFu + ((u >> 16) & 1u);
  return (u16)((u + r) >> 16);
}
__device__ __forceinline__ float bf2f(u16 h) {
  unsigned u = ((unsigned)h) << 16;
  return __builtin_bit_cast(float, u);
}

__device__ __forceinline__ void gload16(const u16* g, u16* l) {
  __builtin_amdgcn_global_load_lds((__attribute__((address_space(1))) const void*)g,
                                   (__attribute__((address_space(3))) void*)l, 16, 0, 0);
}

// ---------- prep: transpose x AND base [B,C,T] -> [B,T,C]; x split hi/lo bf16, base to f32
__global__ __launch_bounds__(256) void transpose_xb_kernel(
    const float* __restrict__ x, const float* __restrict__ base,
    u16* __restrict__ oh, u16* __restrict__ ol, float* __restrict__ of)
{
  __shared__ float tx_[32][33];
  __shared__ float tb_[32][33];
  const int tx = threadIdx.x, ty = threadIdx.y;
  const long cbase = (long)blockIdx.z * C_ + blockIdx.y * 32;
  const long xbase = (long)blockIdx.x * 32;
  const float* ipx = x + cbase * T_ + xbase;
  const float* ipb = base + cbase * T_ + xbase;
#pragma unroll
  for (int i = 0; i < 4; ++i) {
    tx_[ty + i * 8][tx] = ipx[(long)(ty + i * 8) * T_ + tx];
    tb_[ty + i * 8][tx] = ipb[(long)(ty + i * 8) * T_ + tx];
  }
  __syncthreads();
  const long obase = ((long)blockIdx.z * T_ + xbase) * C_ + blockIdx.y * 32;
#pragma unroll
  for (int i = 0; i < 4; ++i) {
    long idx = obase + (long)(ty + i * 8) * C_ + tx;
    float v = tx_[tx][ty + i * 8];
    u16 h = f2bf(v);
    oh[idx] = h;
    ol[idx] = f2bf(v - bf2f(h));
    of[idx] = tb_[tx][ty + i * 8];
  }
}

// ---------- prep: transpose [B,C,X] -> [B,X,C], split to bf16 hi/lo
__global__ __launch_bounds__(256) void transpose_kernel(
    const float* __restrict__ in, u16* __restrict__ oh, u16* __restrict__ ol, int X)
{
  __shared__ float t[32][33];
  const int tx = threadIdx.x, ty = threadIdx.y;
  const long cbase = (long)blockIdx.z * C_ + blockIdx.y * 32;
  const long xbase = (long)blockIdx.x * 32;
  const float* ip = in + cbase * X + xbase;
#pragma unroll
  for (int i = 0; i < 4; ++i)
    t[ty + i * 8][tx] = ip[(long)(ty + i * 8) * X + tx];
  __syncthreads();
  const long obase = ((long)blockIdx.z * X + xbase) * C_ + blockIdx.y * 32;
#pragma unroll
  for (int i = 0; i < 4; ++i) {
    float v = t[tx][ty + i * 8];
    long idx = obase + (long)(ty + i * 8) * C_ + tx;
    u16 h = f2bf(v);
    oh[idx] = h;
    ol[idx] = f2bf(v - bf2f(h));
  }
}

// ---------- prep: elementwise split f32 -> bf16 hi (and optional lo), no transpose
__global__ __launch_bounds__(256) void split_kernel(
    const float* __restrict__ in, u16* __restrict__ oh, u16* __restrict__ ol, long n4)
{
  long i = (long)blockIdx.x * 256 + threadIdx.x;
  const long stride = (long)gridDim.x * 256;
  for (; i < n4; i += stride) {
    f4 v = ((const f4*)in)[i];
    u16x4 hv, lv;
#pragma unroll
    for (int j = 0; j < 4; ++j) {
      u16 h = f2bf(v[j]);
      hv[j] = h;
      lv[j] = f2bf(v[j] - bf2f(h));
    }
    ((u16x4*)oh)[i] = hv;
    if (ol) ((u16x4*)ol)[i] = lv;
  }
}

// ---------- GEMM: out[M][N] = A[M][K] * B[N][K]^T  (both operands K-contiguous rows)
// NPASS=3: hi/lo split 3-pass accumulate (near-f32). NPASS=1: plain bf16.
// EPI=1: target epilogue (+baseT +bias, *SCALE, split-store hi/lo). EPI=0: f32 store.
template<int NPASS, int EPI>
__global__ __launch_bounds__(256, 2) void gemm_kernel(
    const u16* __restrict__ Ah, const u16* __restrict__ Al,
    const u16* __restrict__ Bh, const u16* __restrict__ Bl,
    int M, int N, int K,
    long sA, long sB, long sO,
    const float* __restrict__ baseT, const float* __restrict__ bias,
    u16* __restrict__ outH, u16* __restrict__ outL,
    float* __restrict__ outF)
{
  constexpr int BM = 128, BN = 128, BK = 32;
  constexpr int TILE = BM * BK;
  __shared__ u16 lA[(NPASS == 3 ? 2 : 1) * TILE];
  __shared__ u16 lB[(NPASS == 3 ? 2 : 1) * TILE];
  u16* lAh = lA; u16* lAl = (NPASS == 3) ? (lA + TILE) : lA;
  u16* lBh = lB; u16* lBl = (NPASS == 3) ? (lB + TILE) : lB;

  const int tid = threadIdx.x;
  const int wid = tid >> 6;
  const int lane = tid & 63;
  const int wr = wid >> 1, wc = wid & 1;
  const int bz = blockIdx.z;
  const int m0 = blockIdx.y * BM;
  const int n0 = blockIdx.x * BN;

  const u16* gAh = Ah + (long)bz * sA + (long)m0 * K;
  const u16* gAl = (NPASS == 3) ? (Al + (long)bz * sA + (long)m0 * K) : nullptr;
  const u16* gBh = Bh + (long)bz * sB + (long)n0 * K;
  const u16* gBl = (NPASS == 3) ? (Bl + (long)bz * sB + (long)n0 * K) : nullptr;

  const int srow = tid >> 2;         // staging row 0..63 (per 64-row half)
  const int skoff = (tid & 3) * 8;   // staging k-offset (elements)
  const int ldsOff = wid * 512;      // wave-uniform LDS dest (u16 units)

  f4 acc[4][4] = {};

  for (int k0 = 0; k0 < K; k0 += BK) {
    __syncthreads();
#pragma unroll
    for (int c = 0; c < 2; ++c) {
      const long go = (long)(c * 64 + srow) * K + k0 + skoff;
      const int lo = c * 2048 + ldsOff;
      gload16(gAh + go, lAh + lo);
      if (NPASS == 3) gload16(gAl + go, lAl + lo);
      gload16(gBh + go, lBh + lo);
      if (NPASS == 3) gload16(gBl + go, lBl + lo);
    }
    asm volatile("s_waitcnt vmcnt(0)" ::: "memory");
    __syncthreads();

    bf8 a_h[4], b_h[4], a_l[4], b_l[4];
    const int fr = lane & 15;
    const int fk = (lane >> 4) * 8;
#pragma unroll
    for (int i = 0; i < 4; ++i) {
      a_h[i] = *(const bf8*)&lAh[(wr * 64 + i * 16 + fr) * BK + fk];
      b_h[i] = *(const bf8*)&lBh[(wc * 64 + i * 16 + fr) * BK + fk];
      if (NPASS == 3) {
        a_l[i] = *(const bf8*)&lAl[(wr * 64 + i * 16 + fr) * BK + fk];
        b_l[i] = *(const bf8*)&lBl[(wc * 64 + i * 16 + fr) * BK + fk];
      }
    }
#pragma unroll
    for (int mi = 0; mi < 4; ++mi)
#pragma unroll
      for (int ni = 0; ni < 4; ++ni) {
        acc[mi][ni] = __builtin_amdgcn_mfma_f32_16x16x32_bf16(a_h[mi], b_h[ni], acc[mi][ni], 0, 0, 0);
        if (NPASS == 3) {
          acc[mi][ni] = __builtin_amdgcn_mfma_f32_16x16x32_bf16(a_h[mi], b_l[ni], acc[mi][ni], 0, 0, 0);
          acc[mi][ni] = __builtin_amdgcn_mfma_f32_16x16x32_bf16(a_l[mi], b_h[ni], acc[mi][ni], 0, 0, 0);
        }
      }
  }

  const int fr = lane & 15;
  const int r4 = (lane >> 4) * 4;
#pragma unroll
  for (int mi = 0; mi < 4; ++mi) {
#pragma unroll
    for (int ni = 0; ni < 4; ++ni) {
      const int gn = n0 + wc * 64 + ni * 16 + fr;
#pragma unroll
      for (int r = 0; r < 4; ++r) {
        const long gm = m0 + wr * 64 + mi * 16 + r4 + r;
        const long idx = (long)bz * sO + gm * (long)N + gn;
        const float v = acc[mi][ni][r];
        if (EPI == 1) {
          float val = (v + baseT[idx] + bias[gn]) * SCALE_W;
          u16 h = f2bf(val);
          outH[idx] = h;
          outL[idx] = f2bf(val - bf2f(h));
        } else {
          outF[idx] = v;
        }
      }
    }
  }
}

// ---------- softmax over last dim (rows of 2048 f32), in place + bf16 copy out
__global__ __launch_bounds__(256) void softmax_kernel(float* __restrict__ a,
                                                      u16* __restrict__ ab) {
  const int tid = threadIdx.x;
  float* p = a + (long)blockIdx.x * 2048;
  u16* pb = ab + (long)blockIdx.x * 2048;
  f4 v0 = ((const f4*)p)[tid];
  f4 v1 = ((const f4*)p)[tid + 256];
  float m = fmaxf(fmaxf(fmaxf(v0[0], v0[1]), fmaxf(v0[2], v0[3])),
                  fmaxf(fmaxf(v1[0], v1[1]), fmaxf(v1[2], v1[3])));
#pragma unroll
  for (int o = 32; o >= 1; o >>= 1) m = fmaxf(m, __shfl_xor(m, o));
  __shared__ float redm[4], reds[4];
  if ((tid & 63) == 0) redm[tid >> 6] = m;
  __syncthreads();
  m = fmaxf(fmaxf(redm[0], redm[1]), fmaxf(redm[2], redm[3]));
  float s = 0.f;
#pragma unroll
  for (int j = 0; j < 4; ++j) { v0[j] = __expf(v0[j] - m); s += v0[j]; }
#pragma unroll
  for (int j = 0; j < 4; ++j) { v1[j] = __expf(v1[j] - m); s += v1[j]; }
#pragma unroll
  for (int o = 32; o >= 1; o >>= 1) s += __shfl_xor(s, o);
  if ((tid & 63) == 0) reds[tid >> 6] = s;
  __syncthreads();
  const float inv = 1.0f / (reds[0] + reds[1] + reds[2] + reds[3]);
  v0 *= inv; v1 *= inv;
  ((f4*)p)[tid] = v0;
  ((f4*)p)[tid + 256] = v1;
  u16x4 b0, b1;
#pragma unroll
  for (int j = 0; j < 4; ++j) { b0[j] = f2bf(v0[j]); b1[j] = f2bf(v1[j]); }
  ((u16x4*)pb)[tid] = b0;
  ((u16x4*)pb)[tid + 256] = b1;
}

extern "C" void kernel_launch(void* const* d_in, const int* in_sizes, int n_in,
                              void* d_out, int out_size, void* d_ws, size_t ws_size,
                              hipStream_t stream) {
  const float* base  = (const float*)d_in[0];
  const float* x     = (const float*)d_in[1];
  const float* enc_t = (const float*)d_in[2];
  const float* enc_c = (const float*)d_in[3];
  const float* W     = (const float*)d_in[4];
  const float* bias  = (const float*)d_in[5];

  float* ctx  = (float*)d_out;                       // [B,C,T]
  float* attn = ctx + (long)B_ * C_ * T_;            // [B,T,S]

  const long NBTC = (long)B_ * T_ * C_;              // 8388608
  u16* x_hi  = (u16*)d_ws;
  u16* x_lo  = x_hi + NBTC;
  u16* et_hi = x_lo + NBTC;
  u16* et_lo = et_hi + NBTC;
  u16* ec_hi = et_lo + NBTC;
  float* baseT = (float*)(ec_hi + NBTC);
  u16* w_hi  = (u16*)(baseT + NBTC);
  u16* w_lo  = w_hi + (long)C_ * C_;

  // target hi/lo splits live in the d_out ctx region (dead until final GEMM)
  u16* t_hi = (u16*)d_out;
  u16* t_lo = t_hi + NBTC;
  // attn bf16 copy aliases x_hi..et_lo (4*NBTC u16 = exactly B*T*S), all dead
  // by the time softmax writes it (x after GEMM1, et after GEMM2).
  u16* attn_bf = x_hi;

  dim3 tb(32, 8);
  // x,base [B,C,T] -> x_hi/x_lo bf16, baseT f32, all [B,T,C]
  transpose_xb_kernel<<<dim3(T_ / 32, C_ / 32, B_), tb, 0, stream>>>(x, base, x_hi, x_lo, baseT);
  // enc_t [B,C,S] -> et_hi/et_lo [B,S,C]
  transpose_kernel<<<dim3(S_ / 32, C_ / 32, B_), tb, 0, stream>>>(enc_t, et_hi, et_lo, S_);
  // enc_c [B,C,S] -> ec_hi bf16 (no transpose, hi only)
  split_kernel<<<2048, 256, 0, stream>>>(enc_c, ec_hi, nullptr, (long)B_ * C_ * S_ / 4);
  // W -> w_hi/w_lo
  split_kernel<<<256, 256, 0, stream>>>(W, w_hi, w_lo, (long)C_ * C_ / 4);

  // GEMM1: target^T[t][o] = sum_c x^T[t][c] * W[o][c]; epilogue +baseT +bias, *scale, split
  gemm_kernel<3, 1><<<dim3(C_ / 128, T_ / 128, B_), 256, 0, stream>>>(
      x_hi, x_lo, w_hi, w_lo,
      T_, C_, C_, (long)T_ * C_, 0L, (long)T_ * C_,
      baseT, bias, t_hi, t_lo, nullptr);

  // GEMM2: pre_a[t][s] = sum_c target^T[t][c] * et[s][c]  -> attn region (f32)
  gemm_kernel<3, 0><<<dim3(S_ / 128, T_ / 128, B_), 256, 0, stream>>>(
      t_hi, t_lo, et_hi, et_lo,
      T_, S_, C_, (long)T_ * C_, (long)S_ * C_, (long)T_ * S_,
      nullptr, nullptr, nullptr, nullptr, attn);

  // softmax rows in place + bf16 copy
  softmax_kernel<<<B_ * T_, 256, 0, stream>>>(attn, attn_bf);

  // GEMM3: ctx[c][t] = sum_s ec[c][s] * attn_bf[t][s]
  gemm_kernel<1, 0><<<dim3(T_ / 128, C_ / 128, B_), 256, 0, stream>>>(
      ec_hi, nullptr, attn_bf, nullptr,
      C_, T_, S_, (long)C_ * S_, (long)T_ * S_, (long)C_ * T_,
      nullptr, nullptr, nullptr, nullptr, ctx);

  (void)in_sizes; (void)n_in; (void)out_size; (void)ws_size;
}

// Round 4
// 306.216 us; speedup vs baseline: 1.0875x; 1.0654x over previous
//
#include <hip/hip_runtime.h>

typedef unsigned short u16;
typedef __attribute__((ext_vector_type(4))) float f4;
typedef __attribute__((ext_vector_type(8))) short bf8;
typedef __attribute__((ext_vector_type(4))) unsigned short u16x4;

#define B_ 8
#define C_ 512
#define T_ 2048
#define S_ 2048
#define SCALE_W 0.70710678118654752440f

__device__ __forceinline__ u16 f2bf(float f) {
  unsigned u = __builtin_bit_cast(unsigned, f);
  unsigned r = 0x7FFFu + ((u >> 16) & 1u);
  return (u16)((u + r) >> 16);
}
__device__ __forceinline__ float bf2f(u16 h) {
  unsigned u = ((unsigned)h) << 16;
  return __builtin_bit_cast(float, u);
}

__device__ __forceinline__ void gload16(const u16* g, u16* l) {
  __builtin_amdgcn_global_load_lds((__attribute__((address_space(1))) const void*)g,
                                   (__attribute__((address_space(3))) void*)l, 16, 0, 0);
}

#define MEMF() asm volatile("" ::: "memory")
#define BAR()  do { MEMF(); __builtin_amdgcn_s_barrier(); MEMF(); } while (0)
#define LGKM0() do { asm volatile("s_waitcnt lgkmcnt(0)" ::: "memory"); \
                     __builtin_amdgcn_sched_barrier(0); } while (0)

// ---------- prep: transpose [B,C,X] -> [B,X,C], split to bf16 hi/lo
__global__ __launch_bounds__(256) void transpose_kernel(
    const float* __restrict__ in, u16* __restrict__ oh, u16* __restrict__ ol, int X)
{
  __shared__ float t[32][33];
  const int tx = threadIdx.x, ty = threadIdx.y;
  const long cbase = (long)blockIdx.z * C_ + blockIdx.y * 32;
  const long xbase = (long)blockIdx.x * 32;
  const float* ip = in + cbase * X + xbase;
#pragma unroll
  for (int i = 0; i < 4; ++i)
    t[ty + i * 8][tx] = ip[(long)(ty + i * 8) * X + tx];
  __syncthreads();
  const long obase = ((long)blockIdx.z * X + xbase) * C_ + blockIdx.y * 32;
#pragma unroll
  for (int i = 0; i < 4; ++i) {
    float v = t[tx][ty + i * 8];
    long idx = obase + (long)(ty + i * 8) * C_ + tx;
    u16 h = f2bf(v);
    oh[idx] = h;
    ol[idx] = f2bf(v - bf2f(h));
  }
}

// ---------- prep: elementwise split f32 -> bf16 hi (and optional lo)
__global__ __launch_bounds__(256) void split_kernel(
    const float* __restrict__ in, u16* __restrict__ oh, u16* __restrict__ ol, long n4)
{
  long i = (long)blockIdx.x * 256 + threadIdx.x;
  const long stride = (long)gridDim.x * 256;
  for (; i < n4; i += stride) {
    f4 v = ((const f4*)in)[i];
    u16x4 hv, lv;
#pragma unroll
    for (int j = 0; j < 4; ++j) {
      u16 h = f2bf(v[j]);
      hv[j] = h;
      lv[j] = f2bf(v[j] - bf2f(h));
    }
    ((u16x4*)oh)[i] = hv;
    if (ol) ((u16x4*)ol)[i] = lv;
  }
}

// ---------- old-structure GEMM (128x128, BK=32): out[M][N] = A[M][K] * B[N][K]^T
// NPASS=3: hi/lo 3-pass. EPI=1: +base(original [B,C,T] layout)+bias, *SCALE, hi/lo store.
template<int NPASS, int EPI>
__global__ __launch_bounds__(256, 2) void gemm_kernel(
    const u16* __restrict__ Ah, const u16* __restrict__ Al,
    const u16* __restrict__ Bh, const u16* __restrict__ Bl,
    int M, int N, int K,
    long sA, long sB, long sO,
    const float* __restrict__ baseO, const float* __restrict__ bias,
    u16* __restrict__ outH, u16* __restrict__ outL,
    float* __restrict__ outF)
{
  constexpr int BM = 128, BK = 32;
  constexpr int TILE = BM * BK;
  __shared__ u16 lA[(NPASS == 3 ? 2 : 1) * TILE];
  __shared__ u16 lB[(NPASS == 3 ? 2 : 1) * TILE];
  u16* lAh = lA; u16* lAl = (NPASS == 3) ? (lA + TILE) : lA;
  u16* lBh = lB; u16* lBl = (NPASS == 3) ? (lB + TILE) : lB;

  const int tid = threadIdx.x;
  const int wid = tid >> 6;
  const int lane = tid & 63;
  const int wr = wid >> 1, wc = wid & 1;
  const int bz = blockIdx.z;
  const int m0 = blockIdx.y * BM;
  const int n0 = blockIdx.x * BM;

  const u16* gAh = Ah + (long)bz * sA + (long)m0 * K;
  const u16* gAl = (NPASS == 3) ? (Al + (long)bz * sA + (long)m0 * K) : nullptr;
  const u16* gBh = Bh + (long)bz * sB + (long)n0 * K;
  const u16* gBl = (NPASS == 3) ? (Bl + (long)bz * sB + (long)n0 * K) : nullptr;

  const int srow = tid >> 2;
  const int skoff = (tid & 3) * 8;
  const int ldsOff = wid * 512;

  f4 acc[4][4] = {};

  for (int k0 = 0; k0 < K; k0 += BK) {
    __syncthreads();
#pragma unroll
    for (int c = 0; c < 2; ++c) {
      const long go = (long)(c * 64 + srow) * K + k0 + skoff;
      const int lo = c * 2048 + ldsOff;
      gload16(gAh + go, lAh + lo);
      if (NPASS == 3) gload16(gAl + go, lAl + lo);
      gload16(gBh + go, lBh + lo);
      if (NPASS == 3) gload16(gBl + go, lBl + lo);
    }
    asm volatile("s_waitcnt vmcnt(0)" ::: "memory");
    __syncthreads();

    bf8 a_h[4], b_h[4], a_l[4], b_l[4];
    const int fr = lane & 15;
    const int fk = (lane >> 4) * 8;
#pragma unroll
    for (int i = 0; i < 4; ++i) {
      a_h[i] = *(const bf8*)&lAh[(wr * 64 + i * 16 + fr) * BK + fk];
      b_h[i] = *(const bf8*)&lBh[(wc * 64 + i * 16 + fr) * BK + fk];
      if (NPASS == 3) {
        a_l[i] = *(const bf8*)&lAl[(wr * 64 + i * 16 + fr) * BK + fk];
        b_l[i] = *(const bf8*)&lBl[(wc * 64 + i * 16 + fr) * BK + fk];
      }
    }
#pragma unroll
    for (int mi = 0; mi < 4; ++mi)
#pragma unroll
      for (int ni = 0; ni < 4; ++ni) {
        acc[mi][ni] = __builtin_amdgcn_mfma_f32_16x16x32_bf16(a_h[mi], b_h[ni], acc[mi][ni], 0, 0, 0);
        if (NPASS == 3) {
          acc[mi][ni] = __builtin_amdgcn_mfma_f32_16x16x32_bf16(a_h[mi], b_l[ni], acc[mi][ni], 0, 0, 0);
          acc[mi][ni] = __builtin_amdgcn_mfma_f32_16x16x32_bf16(a_l[mi], b_h[ni], acc[mi][ni], 0, 0, 0);
        }
      }
  }

  const int fr = lane & 15;
  const int r4 = (lane >> 4) * 4;
#pragma unroll
  for (int mi = 0; mi < 4; ++mi) {
#pragma unroll
    for (int ni = 0; ni < 4; ++ni) {
      const int gn = n0 + wc * 64 + ni * 16 + fr;
      const long gmb = m0 + wr * 64 + mi * 16 + r4;
      if (EPI == 1) {
        // base in original [B][C][T] layout: channel gn, t = gmb..gmb+3 (f4 aligned)
        f4 bv = *(const f4*)(baseO + ((long)bz * C_ + gn) * T_ + gmb);
        const float bs = bias[gn];
#pragma unroll
        for (int r = 0; r < 4; ++r) {
          float val = (acc[mi][ni][r] + bv[r] + bs) * SCALE_W;
          const long idx = (long)bz * sO + (gmb + r) * (long)N + gn;
          u16 h = f2bf(val);
          outH[idx] = h;
          outL[idx] = f2bf(val - bf2f(h));
        }
      } else {
#pragma unroll
        for (int r = 0; r < 4; ++r)
          outF[(long)bz * sO + (gmb + r) * (long)N + gn] = acc[mi][ni][r];
      }
    }
  }
}

// ---------- 256x256 / BK=64 / 8-wave phase-pipelined GEMM (counted vmcnt, st_16x32 swizzle)
// Computes pre_a[t][s] = Ah.Bh + Ah.Bl + Al.Bh over K=512 via 24 k-tiles of 64:
// tiles 0-7: Ah x Bh; 8-15: Ah x Bl; 16-23: Al x Bh. All operands K-contiguous, stride C_.
__device__ __forceinline__ void stage2(const u16* g, u16* l) {
  gload16(g, l);
  gload16(g + 64 * C_, l + 4096);
}
template<int NF>
__device__ __forceinline__ void rd_frags(bf8 (&d)[NF][2], const u16* p) {
#pragma unroll
  for (int i = 0; i < NF; ++i)
#pragma unroll
    for (int ks = 0; ks < 2; ++ks)
      d[i][ks] = *(const bf8*)&p[i * 1024 + ks * 32];
}
template<int MH, int NH>
__device__ __forceinline__ void mmq(f4 (&acc)[8][4], const bf8 (&a)[4][2], const bf8 (&b)[2][2]) {
  __builtin_amdgcn_s_setprio(1);
#pragma unroll
  for (int mi = 0; mi < 4; ++mi)
#pragma unroll
    for (int ni = 0; ni < 2; ++ni)
#pragma unroll
      for (int ks = 0; ks < 2; ++ks)
        acc[MH * 4 + mi][NH * 2 + ni] = __builtin_amdgcn_mfma_f32_16x16x32_bf16(
            a[mi][ks], b[ni][ks], acc[MH * 4 + mi][NH * 2 + ni], 0, 0, 0);
  __builtin_amdgcn_s_setprio(0);
}

__global__ __launch_bounds__(512, 2) void gemm8p_kernel(
    const u16* __restrict__ Ah, const u16* __restrict__ Al,
    const u16* __restrict__ Bh, const u16* __restrict__ Bl,
    float* __restrict__ outF)
{
  __shared__ u16 lds[65536];  // A: [2buf][256r][64c] @0 ; B: same @32768 (u16 units)
  const int tid = threadIdx.x;
  const int wid = tid >> 6, lane = tid & 63;
  const int wr = wid >> 2, wc = wid & 3;

  // bijective XCD swizzle (nwg = 512, divisible by 8)
  const int gx = gridDim.x, gy = gridDim.y;
  int lin = blockIdx.x + gx * (blockIdx.y + gy * blockIdx.z);
  const int nwg = gx * gy * (int)gridDim.z;
  lin = (lin & 7) * (nwg >> 3) + (lin >> 3);
  const int bx = lin % gx;
  const int tmp = lin / gx;
  const int by = tmp % gy, bz = tmp / gy;

  const int m0 = by * 256, n0 = bx * 256;
  const u16* gAh = Ah + ((long)bz * T_ + m0) * C_;
  const u16* gAl = Al + ((long)bz * T_ + m0) * C_;
  const u16* gBh = Bh + ((long)bz * S_ + n0) * C_;
  const u16* gBl = Bl + ((long)bz * S_ + n0) * C_;

  // staging geometry: per half-tile (128 rows x 64 cols u16), 2 gloads/thread
  const int srow = tid >> 3;                                        // 0..63
  const int scol = (((tid & 7) * 16) ^ ((srow & 4) ? 32 : 0)) >> 1; // inv-swizzled src col (u16)
  const int dstA = tid * 8;                                         // linear LDS dest (u16)

  // fragment-read geometry (swizzled read matches write)
  const int fr = lane & 15;
  const int kbsw = ((((lane >> 4) * 16) ^ ((lane & 4) ? 32 : 0)) >> 1);
  const int abase = (wr * 128 + fr) * 64 + kbsw;
  const int bbase = 32768 + (wc * 64 + fr) * 64 + kbsw;

  f4 acc[8][4] = {};
  constexpr int NT = 24;

#define SRC_A(tt) ((((tt) >> 3) == 2 ? gAl : gAh) + ((tt) & 7) * 64)
#define SRC_B(tt) ((((tt) >> 3) == 1 ? gBl : gBh) + ((tt) & 7) * 64)
#define STAGE_A(tt, h) stage2(SRC_A(tt) + (long)((h) * 128 + srow) * C_ + scol, \
                              lds + (((tt) & 1) * 16384 + (h) * 8192 + dstA))
#define STAGE_B(tt, h) stage2(SRC_B(tt) + (long)((h) * 128 + srow) * C_ + scol, \
                              lds + (32768 + ((tt) & 1) * 16384 + (h) * 8192 + dstA))

  // prologue: tile0 fully + B(1,0) (10 loads in flight)
  STAGE_B(0, 0); STAGE_B(0, 1); STAGE_A(0, 0); STAGE_A(0, 1); STAGE_B(1, 0);
  asm volatile("s_waitcnt vmcnt(2)" ::: "memory");  // tile0 landed; B(1)h0 may fly
  BAR();

  bf8 af[4][2], b0[2][2], b1[2][2];
  for (int kt = 0; kt < NT - 1; ++kt) {
    const int cur = kt & 1;
    const u16* la = lds + cur * 16384 + abase;
    const u16* lb = lds + cur * 16384 + bbase;
    // ---- ph1: Q(0,0)
    rd_frags(af, la);
    rd_frags(b0, lb);
    STAGE_B(kt + 1, 1);
    BAR(); LGKM0();
    mmq<0, 0>(acc, af, b0);
    BAR();
    // ---- ph2: Q(0,1)
    rd_frags(b1, lb + 2048);
    STAGE_A(kt + 1, 0);
    BAR(); LGKM0();
    mmq<0, 1>(acc, af, b1);
    BAR();
    // ---- ph3: Q(1,0)
    rd_frags(af, la + 4096);
    STAGE_A(kt + 1, 1);
    BAR(); LGKM0();
    mmq<1, 0>(acc, af, b0);
    BAR();
    // ---- ph4: Q(1,1)
    {
      int t2 = kt + 2; if (t2 > NT - 1) t2 = NT - 1;  // harmless duplicate re-stage at tail
      STAGE_B(t2, 0);
    }
    BAR();
    mmq<1, 1>(acc, af, b1);
    if (kt == NT - 2) { asm volatile("s_waitcnt vmcnt(0)" ::: "memory"); }
    else             { asm volatile("s_waitcnt vmcnt(2)" ::: "memory"); }
    BAR();
  }
  // peeled final tile (no staging)
  {
    const int cur = (NT - 1) & 1;
    const u16* la = lds + cur * 16384 + abase;
    const u16* lb = lds + cur * 16384 + bbase;
    rd_frags(af, la);
    rd_frags(b0, lb);
    BAR(); LGKM0();
    mmq<0, 0>(acc, af, b0);
    BAR();
    rd_frags(b1, lb + 2048);
    BAR(); LGKM0();
    mmq<0, 1>(acc, af, b1);
    BAR();
    rd_frags(af, la + 4096);
    BAR(); LGKM0();
    mmq<1, 0>(acc, af, b0);
    BAR();
    mmq<1, 1>(acc, af, b1);
  }
#undef SRC_A
#undef SRC_B
#undef STAGE_A
#undef STAGE_B

  // epilogue: f32 C-write to attn [T][S]
  const int r4 = (lane >> 4) * 4;
#pragma unroll
  for (int am = 0; am < 8; ++am) {
#pragma unroll
    for (int an = 0; an < 4; ++an) {
      const long gm = m0 + wr * 128 + am * 16 + r4;
      const int gn = n0 + wc * 64 + an * 16 + fr;
      float* po = outF + (long)bz * T_ * S_ + gm * (long)S_ + gn;
#pragma unroll
      for (int r = 0; r < 4; ++r) po[(long)r * S_] = acc[am][an][r];
    }
  }
}

// ---------- softmax over last dim (rows of 2048 f32), in place + bf16 copy out
__global__ __launch_bounds__(256) void softmax_kernel(float* __restrict__ a,
                                                      u16* __restrict__ ab) {
  const int tid = threadIdx.x;
  float* p = a + (long)blockIdx.x * 2048;
  u16* pb = ab + (long)blockIdx.x * 2048;
  f4 v0 = ((const f4*)p)[tid];
  f4 v1 = ((const f4*)p)[tid + 256];
  float m = fmaxf(fmaxf(fmaxf(v0[0], v0[1]), fmaxf(v0[2], v0[3])),
                  fmaxf(fmaxf(v1[0], v1[1]), fmaxf(v1[2], v1[3])));
#pragma unroll
  for (int o = 32; o >= 1; o >>= 1) m = fmaxf(m, __shfl_xor(m, o));
  __shared__ float redm[4], reds[4];
  if ((tid & 63) == 0) redm[tid >> 6] = m;
  __syncthreads();
  m = fmaxf(fmaxf(redm[0], redm[1]), fmaxf(redm[2], redm[3]));
  float s = 0.f;
#pragma unroll
  for (int j = 0; j < 4; ++j) { v0[j] = __expf(v0[j] - m); s += v0[j]; }
#pragma unroll
  for (int j = 0; j < 4; ++j) { v1[j] = __expf(v1[j] - m); s += v1[j]; }
#pragma unroll
  for (int o = 32; o >= 1; o >>= 1) s += __shfl_xor(s, o);
  if ((tid & 63) == 0) reds[tid >> 6] = s;
  __syncthreads();
  const float inv = 1.0f / (reds[0] + reds[1] + reds[2] + reds[3]);
  v0 *= inv; v1 *= inv;
  ((f4*)p)[tid] = v0;
  ((f4*)p)[tid + 256] = v1;
  u16x4 c0, c1;
#pragma unroll
  for (int j = 0; j < 4; ++j) { c0[j] = f2bf(v0[j]); c1[j] = f2bf(v1[j]); }
  ((u16x4*)pb)[tid] = c0;
  ((u16x4*)pb)[tid + 256] = c1;
}

extern "C" void kernel_launch(void* const* d_in, const int* in_sizes, int n_in,
                              void* d_out, int out_size, void* d_ws, size_t ws_size,
                              hipStream_t stream) {
  const float* base  = (const float*)d_in[0];
  const float* x     = (const float*)d_in[1];
  const float* enc_t = (const float*)d_in[2];
  const float* enc_c = (const float*)d_in[3];
  const float* W     = (const float*)d_in[4];
  const float* bias  = (const float*)d_in[5];

  float* ctx  = (float*)d_out;                       // [B,C,T]
  float* attn = ctx + (long)B_ * C_ * T_;            // [B,T,S]

  const long NBTC = (long)B_ * T_ * C_;              // 8388608
  u16* x_hi  = (u16*)d_ws;
  u16* x_lo  = x_hi + NBTC;
  u16* et_hi = x_lo + NBTC;
  u16* et_lo = et_hi + NBTC;
  u16* ec_hi = et_lo + NBTC;
  u16* w_hi  = ec_hi + NBTC;
  u16* w_lo  = w_hi + (long)C_ * C_;

  // target hi/lo splits in d_out ctx region (2*NBTC u16 = exactly 32 MB, dead until GEMM3)
  u16* t_hi = (u16*)d_out;
  u16* t_lo = t_hi + NBTC;
  // attn bf16 copy aliases x_hi..et_lo (exactly 4*NBTC u16 = B*T*S), all dead after GEMM2
  u16* attn_bf = x_hi;

  dim3 tb(32, 8);
  // x [B,C,T] -> x_hi/x_lo [B,T,C]
  transpose_kernel<<<dim3(T_ / 32, C_ / 32, B_), tb, 0, stream>>>(x, x_hi, x_lo, T_);
  // enc_t [B,C,S] -> et_hi/et_lo [B,S,C]
  transpose_kernel<<<dim3(S_ / 32, C_ / 32, B_), tb, 0, stream>>>(enc_t, et_hi, et_lo, S_);
  // enc_c -> ec_hi bf16 (no transpose, hi only)
  split_kernel<<<2048, 256, 0, stream>>>(enc_c, ec_hi, nullptr, (long)B_ * C_ * S_ / 4);
  // W -> w_hi/w_lo
  split_kernel<<<256, 256, 0, stream>>>(W, w_hi, w_lo, (long)C_ * C_ / 4);

  // GEMM1 (old structure, 3-pass): target^T[t][o] = sum_c x^T[t][c]*W[o][c];
  // epilogue +base(original layout)+bias, *scale, hi/lo store
  gemm_kernel<3, 1><<<dim3(C_ / 128, T_ / 128, B_), 256, 0, stream>>>(
      x_hi, x_lo, w_hi, w_lo,
      T_, C_, C_, (long)T_ * C_, 0L, (long)T_ * C_,
      base, bias, t_hi, t_lo, nullptr);

  // GEMM2 (256x256 8-phase, 24 k-tiles with hi/lo pointer switching) -> attn f32
  gemm8p_kernel<<<dim3(S_ / 256, T_ / 256, B_), 512, 0, stream>>>(
      t_hi, t_lo, et_hi, et_lo, attn);

  // softmax rows in place + bf16 copy
  softmax_kernel<<<B_ * T_, 256, 0, stream>>>(attn, attn_bf);

  // GEMM3 (old structure, 1-pass): ctx[c][t] = sum_s ec[c][s] * attn_bf[t][s]
  gemm_kernel<1, 0><<<dim3(T_ / 128, C_ / 128, B_), 256, 0, stream>>>(
      ec_hi, nullptr, attn_bf, nullptr,
      C_, T_, S_, (long)C_ * S_, (long)T_ * S_, (long)C_ * T_,
      nullptr, nullptr, nullptr, nullptr, ctx);

  (void)in_sizes; (void)n_in; (void)out_size; (void)ws_size;
}